// Round 2
// baseline (8446.779 us; speedup 1.0000x reference)
//
#include <hip/hip_runtime.h>

// 3-layer LSTM (B=8192, T=336, F=8, H=20) + FC(20->20 relu) + FC(20->1), fp32.
//
// Round 2: spill-proof rewrite of the round-1 mapping.
//  - wave = 3 batch elements x 20 unit-lanes (4 idle); lane (e,j) owns unit j.
//  - NO local arrays / pointer arrays anywhere -> everything in named float4
//    scalars (round 1 spilled ~240 B/thread/t to scratch = 14 GB HBM traffic).
//  - LDS: unpadded row-major weight slabs, strides 8/20 floats (16B aligned,
//    bank-quad period 8 over 20 lanes -> <=3-way aliasing ~ free).
//    Total 38.6 KB -> 4 blocks/CU with __launch_bounds__(256,4).
//  - h exchanged wave-internally through LDS, zero barriers after staging
//    (per-wave DS ops are in-order; verified correct in round 1, absmax 0).

#define T_LEN 336
#define B_TOT 8192

__device__ __forceinline__ float sigm(float x) {
  // 1/(1+exp(-x)) = rcp(1 + 2^(-x*log2e))
  return __builtin_amdgcn_rcpf(1.0f + __builtin_amdgcn_exp2f(-1.4426950408889634f * x));
}
__device__ __forceinline__ float tanh_fast(float x) {
  // tanh(x) = 2/(1+exp(-2x)) - 1
  return 2.0f * __builtin_amdgcn_rcpf(1.0f + __builtin_amdgcn_exp2f(-2.8853900817779268f * x)) - 1.0f;
}

__device__ __forceinline__ float dot8f(const float4* __restrict__ r, float4 a0, float4 a1) {
  float4 w; float s;
  w = r[0]; s  = w.x*a0.x + w.y*a0.y + w.z*a0.z + w.w*a0.w;
  w = r[1]; s += w.x*a1.x + w.y*a1.y + w.z*a1.z + w.w*a1.w;
  return s;
}

__device__ __forceinline__ float dot20f(const float4* __restrict__ r,
                                        float4 a0, float4 a1, float4 a2, float4 a3, float4 a4) {
  float4 w; float s;
  w = r[0]; s  = w.x*a0.x + w.y*a0.y + w.z*a0.z + w.w*a0.w;
  w = r[1]; s += w.x*a1.x + w.y*a1.y + w.z*a1.z + w.w*a1.w;
  w = r[2]; s += w.x*a2.x + w.y*a2.y + w.z*a2.z + w.w*a2.w;
  w = r[3]; s += w.x*a3.x + w.y*a3.y + w.z*a3.z + w.w*a3.w;
  w = r[4]; s += w.x*a4.x + w.y*a4.y + w.z*a4.z + w.w*a4.w;
  return s;
}

#define LSTM_CELL(G0, G1, G2, G3, C, NH)                                   \
  { float ig_ = sigm(G0), fg_ = sigm(G1);                                  \
    float gv_ = tanh_fast(G2), ov_ = sigm(G3);                             \
    C = fg_ * C + ig_ * gv_;                                               \
    NH = ov_ * tanh_fast(C); }

__global__ __launch_bounds__(256, 4) void lstm3_fc_kernel(
    const float* __restrict__ x,
    const float* __restrict__ Wih0, const float* __restrict__ Whh0,
    const float* __restrict__ bih0, const float* __restrict__ bhh0,
    const float* __restrict__ Wih1, const float* __restrict__ Whh1,
    const float* __restrict__ bih1, const float* __restrict__ bhh1,
    const float* __restrict__ Wih2, const float* __restrict__ Whh2,
    const float* __restrict__ bih2, const float* __restrict__ bhh2,
    const float* __restrict__ fc1w, const float* __restrict__ fc1b,
    const float* __restrict__ fc2w, const float* __restrict__ fc2b,
    float* __restrict__ out)
{
  __shared__ float w0x[80 * 8];    // Wih0, row-major (stride 8)
  __shared__ float w0h[80 * 20];   // Whh0 (stride 20)
  __shared__ float w1i[80 * 20];   // Wih1
  __shared__ float w1h[80 * 20];   // Whh1
  __shared__ float w2i[80 * 20];   // Wih2
  __shared__ float w2h[80 * 20];   // Whh2
  __shared__ float cb0[80], cb1[80], cb2[80];
  __shared__ float hs0[13 * 20], hs1[13 * 20], hs2[13 * 20];  // h per layer, stride 20

  const int tid = threadIdx.x;

  // ---- stage weights into LDS (all layouts are straight copies) ----
  for (int i = tid; i < 160; i += 256) ((float4*)w0x)[i] = ((const float4*)Wih0)[i];
  for (int i = tid; i < 400; i += 256) ((float4*)w0h)[i] = ((const float4*)Whh0)[i];
  for (int i = tid; i < 400; i += 256) ((float4*)w1i)[i] = ((const float4*)Wih1)[i];
  for (int i = tid; i < 400; i += 256) ((float4*)w1h)[i] = ((const float4*)Whh1)[i];
  for (int i = tid; i < 400; i += 256) ((float4*)w2i)[i] = ((const float4*)Wih2)[i];
  for (int i = tid; i < 400; i += 256) ((float4*)w2h)[i] = ((const float4*)Whh2)[i];
  for (int i = tid; i < 80; i += 256) {
    cb0[i] = bih0[i] + bhh0[i];
    cb1[i] = bih1[i] + bhh1[i];
    cb2[i] = bih2[i] + bhh2[i];
  }
  for (int i = tid; i < 13 * 20; i += 256) { hs0[i] = 0.f; hs1[i] = 0.f; hs2[i] = 0.f; }
  __syncthreads();   // the only barrier in the kernel

  const int lane = tid & 63;
  const int wv   = tid >> 6;
  const int ew   = lane / 20;          // 0..2 live, 3 = idle
  const int j    = lane - ew * 20;     // hidden unit 0..19
  const bool alive = (ew < 3);
  const int eb   = wv * 3 + ew;        // 0..11 live; idle -> {3,6,9,12} (read-only slots for them)
  const int eg   = blockIdx.x * 12 + eb;
  const bool valid = alive && (eg < B_TOT);

  // x pointer (idle/tail lanes clamp to a nearby valid element; results discarded)
  int egc = eg < B_TOT ? eg : (B_TOT - 1);
  const float4* xp = (const float4*)(x + (long)egc * (T_LEN * 8));

  // h slabs for my element
  const float4* H0 = (const float4*)(hs0 + eb * 20);
  const float4* H1 = (const float4*)(hs1 + eb * 20);
  const float4* H2 = (const float4*)(hs2 + eb * 20);
  float* hw0 = hs0 + eb * 20;
  float* hw1 = hs1 + eb * 20;
  float* hw2 = hs2 + eb * 20;

  // per-lane gate-row pointers (named, no arrays)
  const float4* p0x0 = (const float4*)&w0x[(     j) * 8];
  const float4* p0x1 = (const float4*)&w0x[(20 + j) * 8];
  const float4* p0x2 = (const float4*)&w0x[(40 + j) * 8];
  const float4* p0x3 = (const float4*)&w0x[(60 + j) * 8];
  const float4* p0h0 = (const float4*)&w0h[(     j) * 20];
  const float4* p0h1 = (const float4*)&w0h[(20 + j) * 20];
  const float4* p0h2 = (const float4*)&w0h[(40 + j) * 20];
  const float4* p0h3 = (const float4*)&w0h[(60 + j) * 20];
  const float4* p1i0 = (const float4*)&w1i[(     j) * 20];
  const float4* p1i1 = (const float4*)&w1i[(20 + j) * 20];
  const float4* p1i2 = (const float4*)&w1i[(40 + j) * 20];
  const float4* p1i3 = (const float4*)&w1i[(60 + j) * 20];
  const float4* p1h0 = (const float4*)&w1h[(     j) * 20];
  const float4* p1h1 = (const float4*)&w1h[(20 + j) * 20];
  const float4* p1h2 = (const float4*)&w1h[(40 + j) * 20];
  const float4* p1h3 = (const float4*)&w1h[(60 + j) * 20];
  const float4* p2i0 = (const float4*)&w2i[(     j) * 20];
  const float4* p2i1 = (const float4*)&w2i[(20 + j) * 20];
  const float4* p2i2 = (const float4*)&w2i[(40 + j) * 20];
  const float4* p2i3 = (const float4*)&w2i[(60 + j) * 20];
  const float4* p2h0 = (const float4*)&w2h[(     j) * 20];
  const float4* p2h1 = (const float4*)&w2h[(20 + j) * 20];
  const float4* p2h2 = (const float4*)&w2h[(40 + j) * 20];
  const float4* p2h3 = (const float4*)&w2h[(60 + j) * 20];

  const float b00 = cb0[j], b01 = cb0[20 + j], b02 = cb0[40 + j], b03 = cb0[60 + j];
  const float b10 = cb1[j], b11 = cb1[20 + j], b12 = cb1[40 + j], b13 = cb1[60 + j];
  const float b20 = cb2[j], b21 = cb2[20 + j], b22 = cb2[40 + j], b23 = cb2[60 + j];

  float c0 = 0.f, c1 = 0.f, c2 = 0.f;

#pragma unroll 1
  for (int t = 0; t < T_LEN; ++t) {
    // ---------- layer 0 ----------
    float4 xa = xp[0], xb = xp[1];
    xp += 2;
    float4 a0 = H0[0], a1 = H0[1], a2 = H0[2], a3 = H0[3], a4 = H0[4];
    float g0 = b00 + dot8f(p0x0, xa, xb) + dot20f(p0h0, a0, a1, a2, a3, a4);
    float g1 = b01 + dot8f(p0x1, xa, xb) + dot20f(p0h1, a0, a1, a2, a3, a4);
    float g2 = b02 + dot8f(p0x2, xa, xb) + dot20f(p0h2, a0, a1, a2, a3, a4);
    float g3 = b03 + dot8f(p0x3, xa, xb) + dot20f(p0h3, a0, a1, a2, a3, a4);
    float nh;
    LSTM_CELL(g0, g1, g2, g3, c0, nh);
    if (alive) hw0[j] = nh;              // wave-internal; DS pipe in-order

    // ---------- layer 1 ----------
    a0 = H0[0]; a1 = H0[1]; a2 = H0[2]; a3 = H0[3]; a4 = H0[4];   // fresh h0(t)
    float4 d0 = H1[0], d1 = H1[1], d2 = H1[2], d3 = H1[3], d4 = H1[4];
    g0 = b10 + dot20f(p1i0, a0, a1, a2, a3, a4) + dot20f(p1h0, d0, d1, d2, d3, d4);
    g1 = b11 + dot20f(p1i1, a0, a1, a2, a3, a4) + dot20f(p1h1, d0, d1, d2, d3, d4);
    g2 = b12 + dot20f(p1i2, a0, a1, a2, a3, a4) + dot20f(p1h2, d0, d1, d2, d3, d4);
    g3 = b13 + dot20f(p1i3, a0, a1, a2, a3, a4) + dot20f(p1h3, d0, d1, d2, d3, d4);
    LSTM_CELL(g0, g1, g2, g3, c1, nh);
    if (alive) hw1[j] = nh;

    // ---------- layer 2 ----------
    a0 = H1[0]; a1 = H1[1]; a2 = H1[2]; a3 = H1[3]; a4 = H1[4];   // fresh h1(t)
    d0 = H2[0]; d1 = H2[1]; d2 = H2[2]; d3 = H2[3]; d4 = H2[4];
    g0 = b20 + dot20f(p2i0, a0, a1, a2, a3, a4) + dot20f(p2h0, d0, d1, d2, d3, d4);
    g1 = b21 + dot20f(p2i1, a0, a1, a2, a3, a4) + dot20f(p2h1, d0, d1, d2, d3, d4);
    g2 = b22 + dot20f(p2i2, a0, a1, a2, a3, a4) + dot20f(p2h2, d0, d1, d2, d3, d4);
    g3 = b23 + dot20f(p2i3, a0, a1, a2, a3, a4) + dot20f(p2h3, d0, d1, d2, d3, d4);
    LSTM_CELL(g0, g1, g2, g3, c2, nh);
    if (alive) hw2[j] = nh;
  }

  // ---------- FC head: relu(h2 @ fc1w^T + fc1b) @ fc2w^T + fc2b ----------
  {
    float4 f0 = H2[0], f1 = H2[1], f2 = H2[2], f3 = H2[3], f4 = H2[4];
    float s = fc1b[j] + dot20f((const float4*)(fc1w + j * 20), f0, f1, f2, f3, f4);
    s = fmaxf(s, 0.0f);
    if (alive) hw0[j] = s;               // stage fc1 output in hs0 (wave-internal)
  }
  if (valid && j == 0) {
    float4 q0 = H0[0], q1 = H0[1], q2 = H0[2], q3 = H0[3], q4 = H0[4];
    float r = fc2b[0] + dot20f((const float4*)fc2w, q0, q1, q2, q3, q4);
    out[eg] = r;
  }
}

extern "C" void kernel_launch(void* const* d_in, const int* in_sizes, int n_in,
                              void* d_out, int out_size, void* d_ws, size_t ws_size,
                              hipStream_t stream) {
  const float* x    = (const float*)d_in[0];
  const float* Wih0 = (const float*)d_in[1];
  const float* Whh0 = (const float*)d_in[2];
  const float* bih0 = (const float*)d_in[3];
  const float* bhh0 = (const float*)d_in[4];
  const float* Wih1 = (const float*)d_in[5];
  const float* Whh1 = (const float*)d_in[6];
  const float* bih1 = (const float*)d_in[7];
  const float* bhh1 = (const float*)d_in[8];
  const float* Wih2 = (const float*)d_in[9];
  const float* Whh2 = (const float*)d_in[10];
  const float* bih2 = (const float*)d_in[11];
  const float* bhh2 = (const float*)d_in[12];
  const float* fc1w = (const float*)d_in[13];
  const float* fc1b = (const float*)d_in[14];
  const float* fc2w = (const float*)d_in[15];
  const float* fc2b = (const float*)d_in[16];
  float* out = (float*)d_out;

  const int nblk = (8192 + 11) / 12;   // 683
  hipLaunchKernelGGL(lstm3_fc_kernel, dim3(nblk), dim3(256), 0, stream,
                     x, Wih0, Whh0, bih0, bhh0,
                     Wih1, Whh1, bih1, bhh1,
                     Wih2, Whh2, bih2, bhh2,
                     fc1w, fc1b, fc2w, fc2b, out);
}

// Round 3
// 7094.469 us; speedup vs baseline: 1.1906x; 1.1906x over previous
//
#include <hip/hip_runtime.h>

// 3-layer LSTM (B=8192, T=336, F=8, H=20) + FC(20->20 relu) + FC(20->1), fp32.
//
// Round 3: spill-proof. R1/R2 spilled loop-invariant pointers/biases to
// scratch and re-read ~400 B/thread/step from HBM (FETCH 14-24 GB). Fix:
// ZERO pointer variables; every LDS access is arr[j*20 + CONST] so all
// ds_read_b128 share ~3 base VGPRs (j*80 / eb*80 / j*16 bytes) + immediate
// offsets. Biases live in LDS as float4-per-(layer,j), re-read each step.
// Loop-invariant VGPRs ~8; peak live ~40.
//
// Mapping: wave = 3 elements x 20 unit-lanes (4 idle). h exchanged
// wave-internally through LDS with no barriers (per-wave DS ops in-order;
// verified absmax=0 in R1). Block 256 = 12 elems; grid 683.

#define T_LEN 336
#define B_TOT 8192

__device__ __forceinline__ float sigm(float x) {
  return __builtin_amdgcn_rcpf(1.0f + __builtin_amdgcn_exp2f(-1.4426950408889634f * x));
}
__device__ __forceinline__ float tanh_fast(float x) {
  return 2.0f * __builtin_amdgcn_rcpf(1.0f + __builtin_amdgcn_exp2f(-2.8853900817779268f * x)) - 1.0f;
}
__device__ __forceinline__ float dot4(float4 w, float4 a) {
  return w.x*a.x + w.y*a.y + w.z*a.z + w.w*a.w;
}

#define LD4(arr, idx) (*(const float4*)&(arr)[idx])

__global__ __launch_bounds__(256, 4) void lstm3_fc_kernel(
    const float* __restrict__ x,
    const float* __restrict__ Wih0, const float* __restrict__ Whh0,
    const float* __restrict__ bih0, const float* __restrict__ bhh0,
    const float* __restrict__ Wih1, const float* __restrict__ Whh1,
    const float* __restrict__ bih1, const float* __restrict__ bhh1,
    const float* __restrict__ Wih2, const float* __restrict__ Whh2,
    const float* __restrict__ bih2, const float* __restrict__ bhh2,
    const float* __restrict__ fc1w, const float* __restrict__ fc1b,
    const float* __restrict__ fc2w, const float* __restrict__ fc2b,
    float* __restrict__ out)
{
  __shared__ float w0x[80 * 8];    // Wih0 row-major (row j*8)
  __shared__ float w0h[80 * 20];   // Whh0 (row j*20, gate block +400)
  __shared__ float w1i[80 * 20];
  __shared__ float w1h[80 * 20];
  __shared__ float w2i[80 * 20];
  __shared__ float w2h[80 * 20];
  __shared__ float cbp0[80], cbp1[80], cbp2[80];   // [j][q] packed: float4 per j
  __shared__ float hs0[13 * 20], hs1[13 * 20], hs2[13 * 20];

  const int tid = threadIdx.x;

  // ---- stage weights (straight row-major copies) ----
  for (int i = tid; i < 160; i += 256) ((float4*)w0x)[i] = ((const float4*)Wih0)[i];
  for (int i = tid; i < 400; i += 256) ((float4*)w0h)[i] = ((const float4*)Whh0)[i];
  for (int i = tid; i < 400; i += 256) ((float4*)w1i)[i] = ((const float4*)Wih1)[i];
  for (int i = tid; i < 400; i += 256) ((float4*)w1h)[i] = ((const float4*)Whh1)[i];
  for (int i = tid; i < 400; i += 256) ((float4*)w2i)[i] = ((const float4*)Wih2)[i];
  for (int i = tid; i < 400; i += 256) ((float4*)w2h)[i] = ((const float4*)Whh2)[i];
  // biases packed [j*4 + q]
  for (int i = tid; i < 80; i += 256) {
    int q = i & 3, jj = i >> 2;
    cbp0[i] = bih0[q * 20 + jj] + bhh0[q * 20 + jj];
    cbp1[i] = bih1[q * 20 + jj] + bhh1[q * 20 + jj];
    cbp2[i] = bih2[q * 20 + jj] + bhh2[q * 20 + jj];
  }
  for (int i = tid; i < 13 * 20; i += 256) { hs0[i] = 0.f; hs1[i] = 0.f; hs2[i] = 0.f; }
  __syncthreads();   // only barrier

  const int lane = tid & 63;
  const int wv   = tid >> 6;
  const int ew   = lane / 20;          // 0..2 live, 3 idle
  const int j    = lane - ew * 20;     // unit 0..19
  const bool alive = (ew < 3);
  const int eb   = wv * 3 + ew;        // live 0..11; idle -> 3,6,9,12 (read-only)
  const int eg   = blockIdx.x * 12 + eb;
  const bool valid = alive && (eg < B_TOT);

  const int egc = (eg < B_TOT) ? eg : (B_TOT - 1);
  const float* xpe = x + (long)egc * (T_LEN * 8);

  const int j20 = j * 20;   // weight-row base (shared by 5 slabs)
  const int j8  = j * 8;    // w0x row base
  const int j4  = j * 4;    // bias base
  const int e20 = eb * 20;  // h base
  const int ej  = e20 + j;  // h write index

  float c0 = 0.f, c1 = 0.f, c2 = 0.f;

#pragma unroll 1
  for (int t = 0; t < T_LEN; ++t) {
    float g0, g1, g2, g3, nh;
    float4 w, a;

    // ================= layer 0 =================
    {
      float4 bq = LD4(cbp0, j4);
      g0 = bq.x; g1 = bq.y; g2 = bq.z; g3 = bq.w;
      // x part (global, 2 float4)
      float4 xa = *(const float4*)(xpe + t * 8);
      float4 xb = *(const float4*)(xpe + t * 8 + 4);
      w = LD4(w0x, j8 +   0); g0 += dot4(w, xa);
      w = LD4(w0x, j8 +   4); g0 += dot4(w, xb);
      w = LD4(w0x, j8 + 160); g1 += dot4(w, xa);
      w = LD4(w0x, j8 + 164); g1 += dot4(w, xb);
      w = LD4(w0x, j8 + 320); g2 += dot4(w, xa);
      w = LD4(w0x, j8 + 324); g2 += dot4(w, xb);
      w = LD4(w0x, j8 + 480); g3 += dot4(w, xa);
      w = LD4(w0x, j8 + 484); g3 += dot4(w, xb);
#pragma unroll
      for (int k = 0; k < 5; ++k) {
        a = LD4(hs0, e20 + 4 * k);
        w = LD4(w0h, j20 +    0 + 4 * k); g0 += dot4(w, a);
        w = LD4(w0h, j20 +  400 + 4 * k); g1 += dot4(w, a);
        w = LD4(w0h, j20 +  800 + 4 * k); g2 += dot4(w, a);
        w = LD4(w0h, j20 + 1200 + 4 * k); g3 += dot4(w, a);
      }
      float ig = sigm(g0), fg = sigm(g1), gv = tanh_fast(g2), ov = sigm(g3);
      c0 = fg * c0 + ig * gv;
      nh = ov * tanh_fast(c0);
      if (alive) hs0[ej] = nh;   // wave-internal, DS in-order
    }

    // ================= layer 1 =================
    {
      float4 bq = LD4(cbp1, j4);
      g0 = bq.x; g1 = bq.y; g2 = bq.z; g3 = bq.w;
#pragma unroll
      for (int k = 0; k < 5; ++k) {
        a = LD4(hs0, e20 + 4 * k);           // fresh h0(t)
        w = LD4(w1i, j20 +    0 + 4 * k); g0 += dot4(w, a);
        w = LD4(w1i, j20 +  400 + 4 * k); g1 += dot4(w, a);
        w = LD4(w1i, j20 +  800 + 4 * k); g2 += dot4(w, a);
        w = LD4(w1i, j20 + 1200 + 4 * k); g3 += dot4(w, a);
      }
#pragma unroll
      for (int k = 0; k < 5; ++k) {
        a = LD4(hs1, e20 + 4 * k);           // h1(t-1)
        w = LD4(w1h, j20 +    0 + 4 * k); g0 += dot4(w, a);
        w = LD4(w1h, j20 +  400 + 4 * k); g1 += dot4(w, a);
        w = LD4(w1h, j20 +  800 + 4 * k); g2 += dot4(w, a);
        w = LD4(w1h, j20 + 1200 + 4 * k); g3 += dot4(w, a);
      }
      float ig = sigm(g0), fg = sigm(g1), gv = tanh_fast(g2), ov = sigm(g3);
      c1 = fg * c1 + ig * gv;
      nh = ov * tanh_fast(c1);
      if (alive) hs1[ej] = nh;
    }

    // ================= layer 2 =================
    {
      float4 bq = LD4(cbp2, j4);
      g0 = bq.x; g1 = bq.y; g2 = bq.z; g3 = bq.w;
#pragma unroll
      for (int k = 0; k < 5; ++k) {
        a = LD4(hs1, e20 + 4 * k);           // fresh h1(t)
        w = LD4(w2i, j20 +    0 + 4 * k); g0 += dot4(w, a);
        w = LD4(w2i, j20 +  400 + 4 * k); g1 += dot4(w, a);
        w = LD4(w2i, j20 +  800 + 4 * k); g2 += dot4(w, a);
        w = LD4(w2i, j20 + 1200 + 4 * k); g3 += dot4(w, a);
      }
#pragma unroll
      for (int k = 0; k < 5; ++k) {
        a = LD4(hs2, e20 + 4 * k);           // h2(t-1)
        w = LD4(w2h, j20 +    0 + 4 * k); g0 += dot4(w, a);
        w = LD4(w2h, j20 +  400 + 4 * k); g1 += dot4(w, a);
        w = LD4(w2h, j20 +  800 + 4 * k); g2 += dot4(w, a);
        w = LD4(w2h, j20 + 1200 + 4 * k); g3 += dot4(w, a);
      }
      float ig = sigm(g0), fg = sigm(g1), gv = tanh_fast(g2), ov = sigm(g3);
      c2 = fg * c2 + ig * gv;
      nh = ov * tanh_fast(c2);
      if (alive) hs2[ej] = nh;
    }
  }

  // ================= FC head =================
  {
    float s = fc1b[j];
#pragma unroll
    for (int k = 0; k < 5; ++k) {
      float4 a = LD4(hs2, e20 + 4 * k);
      float4 w = *(const float4*)(fc1w + j20 + 4 * k);
      s += dot4(w, a);
    }
    s = fmaxf(s, 0.0f);
    if (alive) hs0[ej] = s;    // stage fc1 out (wave-internal)
  }
  if (valid && j == 0) {
    float r = fc2b[0];
#pragma unroll
    for (int k = 0; k < 5; ++k) {
      float4 a = LD4(hs0, e20 + 4 * k);
      float4 w = *(const float4*)(fc2w + 4 * k);
      r += dot4(w, a);
    }
    out[eg] = r;
  }
}

extern "C" void kernel_launch(void* const* d_in, const int* in_sizes, int n_in,
                              void* d_out, int out_size, void* d_ws, size_t ws_size,
                              hipStream_t stream) {
  const float* x    = (const float*)d_in[0];
  const float* Wih0 = (const float*)d_in[1];
  const float* Whh0 = (const float*)d_in[2];
  const float* bih0 = (const float*)d_in[3];
  const float* bhh0 = (const float*)d_in[4];
  const float* Wih1 = (const float*)d_in[5];
  const float* Whh1 = (const float*)d_in[6];
  const float* bih1 = (const float*)d_in[7];
  const float* bhh1 = (const float*)d_in[8];
  const float* Wih2 = (const float*)d_in[9];
  const float* Whh2 = (const float*)d_in[10];
  const float* bih2 = (const float*)d_in[11];
  const float* bhh2 = (const float*)d_in[12];
  const float* fc1w = (const float*)d_in[13];
  const float* fc1b = (const float*)d_in[14];
  const float* fc2w = (const float*)d_in[15];
  const float* fc2b = (const float*)d_in[16];
  float* out = (float*)d_out;

  const int nblk = (8192 + 11) / 12;   // 683
  hipLaunchKernelGGL(lstm3_fc_kernel, dim3(nblk), dim3(256), 0, stream,
                     x, Wih0, Whh0, bih0, bhh0,
                     Wih1, Whh1, bih1, bhh1,
                     Wih2, Whh2, bih2, bhh2,
                     fc1w, fc1b, fc2w, fc2b, out);
}

// Round 4
// 1717.995 us; speedup vs baseline: 4.9166x; 4.1295x over previous
//
#include <hip/hip_runtime.h>

// 3-layer LSTM (B=8192, T=336, F=8, H=20) + FC(20->20 relu) + FC(20->1), fp32.
//
// Round 4: two changes.
// (1) LICM-blocker: asm volatile memory clobber inside the t-loop. R1-R3 the
//     compiler hoisted the ~108 loop-invariant LDS weight loads out of the
//     336-step loop, spilled them to scratch, and re-read ~400 B/thread/step
//     from HBM (FETCH 14-23 GB). The clobber pins every LDS read inside the
//     loop body: ds_read (~10 cyc) instead of HBM scratch (~900 cyc).
// (2) E=2 elements per lane: each weight float4 feeds 2 elements' FMAs,
//     halving per-element weight traffic on the LDS pipe (the post-fix
//     bottleneck). Wave = 3 groups x 20 unit-lanes, each group 2 elements.
//     Block = 128 thr (2 waves) = 12 elems; grid = 683; ~2.67 blocks/CU.
//
// h exchanged wave-internally through LDS, no barriers in the loop (per-wave
// DS ops are in-order; verified absmax=0 in R1/R3).

#define T_LEN 336
#define B_TOT 8192

__device__ __forceinline__ float sigm(float x) {
  return __builtin_amdgcn_rcpf(1.0f + __builtin_amdgcn_exp2f(-1.4426950408889634f * x));
}
__device__ __forceinline__ float tanh_fast(float x) {
  return 2.0f * __builtin_amdgcn_rcpf(1.0f + __builtin_amdgcn_exp2f(-2.8853900817779268f * x)) - 1.0f;
}
__device__ __forceinline__ float dot4(float4 w, float4 a) {
  return w.x*a.x + w.y*a.y + w.z*a.z + w.w*a.w;
}

#define LD4(arr, idx) (*(const float4*)&(arr)[idx])

__global__ __launch_bounds__(128, 4) void lstm3_fc_kernel(
    const float* __restrict__ x,
    const float* __restrict__ Wih0, const float* __restrict__ Whh0,
    const float* __restrict__ bih0, const float* __restrict__ bhh0,
    const float* __restrict__ Wih1, const float* __restrict__ Whh1,
    const float* __restrict__ bih1, const float* __restrict__ bhh1,
    const float* __restrict__ Wih2, const float* __restrict__ Whh2,
    const float* __restrict__ bih2, const float* __restrict__ bhh2,
    const float* __restrict__ fc1w, const float* __restrict__ fc1b,
    const float* __restrict__ fc2w, const float* __restrict__ fc2b,
    float* __restrict__ out)
{
  __shared__ float w0x[80 * 8];    // Wih0 row-major (row j*8)
  __shared__ float w0h[80 * 20];   // Whh0 (row j*20, gate block +400)
  __shared__ float w1i[80 * 20];
  __shared__ float w1h[80 * 20];
  __shared__ float w2i[80 * 20];
  __shared__ float w2h[80 * 20];
  __shared__ float cbp0[80], cbp1[80], cbp2[80];   // packed [j*4+q]
  __shared__ float hs0[13 * 20], hs1[13 * 20], hs2[13 * 20]; // 12 live + dummy slot 12

  const int tid = threadIdx.x;

  // ---- stage weights (row-major copies) ----
  for (int i = tid; i < 160; i += 128) ((float4*)w0x)[i] = ((const float4*)Wih0)[i];
  for (int i = tid; i < 400; i += 128) ((float4*)w0h)[i] = ((const float4*)Whh0)[i];
  for (int i = tid; i < 400; i += 128) ((float4*)w1i)[i] = ((const float4*)Wih1)[i];
  for (int i = tid; i < 400; i += 128) ((float4*)w1h)[i] = ((const float4*)Whh1)[i];
  for (int i = tid; i < 400; i += 128) ((float4*)w2i)[i] = ((const float4*)Wih2)[i];
  for (int i = tid; i < 400; i += 128) ((float4*)w2h)[i] = ((const float4*)Whh2)[i];
  for (int i = tid; i < 80; i += 128) {
    int q = i & 3, jj = i >> 2;
    cbp0[i] = bih0[q * 20 + jj] + bhh0[q * 20 + jj];
    cbp1[i] = bih1[q * 20 + jj] + bhh1[q * 20 + jj];
    cbp2[i] = bih2[q * 20 + jj] + bhh2[q * 20 + jj];
  }
  for (int i = tid; i < 13 * 20; i += 128) { hs0[i] = 0.f; hs1[i] = 0.f; hs2[i] = 0.f; }
  __syncthreads();   // only barrier

  const int lane = tid & 63;
  const int wv   = tid >> 6;
  const int ew   = lane / 20;          // 0..2 live, 3 idle
  const int j    = lane - ew * 20;     // unit 0..19
  const bool alive = (ew < 3);
  // element slots: live lanes own 2 elements; idle lanes use dummy slot 12
  const int ebA = alive ? (wv * 6 + ew * 2)     : 12;
  const int ebB = alive ? (wv * 6 + ew * 2 + 1) : 12;
  const int egA = blockIdx.x * 12 + ebA;
  const int egB = blockIdx.x * 12 + ebB;

  const int egcA = (egA < B_TOT) ? egA : (B_TOT - 1);
  const int egcB = (egB < B_TOT) ? egB : (B_TOT - 1);
  const float* xpA = x + (long)egcA * (T_LEN * 8);
  const float* xpB = x + (long)egcB * (T_LEN * 8);

  const int j20 = j * 20;
  const int j8  = j * 8;
  const int j4  = j * 4;
  const int eA20 = ebA * 20;
  const int eB20 = ebB * 20;

  float cA0 = 0.f, cA1 = 0.f, cA2 = 0.f;
  float cB0 = 0.f, cB1 = 0.f, cB2 = 0.f;

#pragma unroll 1
  for (int t = 0; t < T_LEN; ++t) {
    asm volatile("" ::: "memory");   // forbid hoisting LDS loads out of the loop
    float4 w, a, b;

    // ================= layer 0 =================
    {
      float4 bq = LD4(cbp0, j4);
      float gA0 = bq.x, gA1 = bq.y, gA2 = bq.z, gA3 = bq.w;
      float gB0 = bq.x, gB1 = bq.y, gB2 = bq.z, gB3 = bq.w;
      float4 xa = *(const float4*)(xpA + t * 8);
      float4 xb = *(const float4*)(xpA + t * 8 + 4);
      float4 ya = *(const float4*)(xpB + t * 8);
      float4 yb = *(const float4*)(xpB + t * 8 + 4);
      w = LD4(w0x, j8 +   0); gA0 += dot4(w, xa); gB0 += dot4(w, ya);
      w = LD4(w0x, j8 +   4); gA0 += dot4(w, xb); gB0 += dot4(w, yb);
      w = LD4(w0x, j8 + 160); gA1 += dot4(w, xa); gB1 += dot4(w, ya);
      w = LD4(w0x, j8 + 164); gA1 += dot4(w, xb); gB1 += dot4(w, yb);
      w = LD4(w0x, j8 + 320); gA2 += dot4(w, xa); gB2 += dot4(w, ya);
      w = LD4(w0x, j8 + 324); gA2 += dot4(w, xb); gB2 += dot4(w, yb);
      w = LD4(w0x, j8 + 480); gA3 += dot4(w, xa); gB3 += dot4(w, ya);
      w = LD4(w0x, j8 + 484); gA3 += dot4(w, xb); gB3 += dot4(w, yb);
#pragma unroll
      for (int k = 0; k < 5; ++k) {
        a = LD4(hs0, eA20 + 4 * k);
        b = LD4(hs0, eB20 + 4 * k);
        w = LD4(w0h, j20 +    0 + 4 * k); gA0 += dot4(w, a); gB0 += dot4(w, b);
        w = LD4(w0h, j20 +  400 + 4 * k); gA1 += dot4(w, a); gB1 += dot4(w, b);
        w = LD4(w0h, j20 +  800 + 4 * k); gA2 += dot4(w, a); gB2 += dot4(w, b);
        w = LD4(w0h, j20 + 1200 + 4 * k); gA3 += dot4(w, a); gB3 += dot4(w, b);
      }
      float iA = sigm(gA0), fA = sigm(gA1), gA = tanh_fast(gA2), oA = sigm(gA3);
      cA0 = fA * cA0 + iA * gA;
      float nhA = oA * tanh_fast(cA0);
      float iB = sigm(gB0), fB = sigm(gB1), gB = tanh_fast(gB2), oB = sigm(gB3);
      cB0 = fB * cB0 + iB * gB;
      float nhB = oB * tanh_fast(cB0);
      if (alive) { hs0[eA20 + j] = nhA; hs0[eB20 + j] = nhB; }  // wave-internal
    }

    // ================= layer 1 =================
    {
      float4 bq = LD4(cbp1, j4);
      float gA0 = bq.x, gA1 = bq.y, gA2 = bq.z, gA3 = bq.w;
      float gB0 = bq.x, gB1 = bq.y, gB2 = bq.z, gB3 = bq.w;
#pragma unroll
      for (int k = 0; k < 5; ++k) {
        a = LD4(hs0, eA20 + 4 * k);          // fresh h0(t)
        b = LD4(hs0, eB20 + 4 * k);
        w = LD4(w1i, j20 +    0 + 4 * k); gA0 += dot4(w, a); gB0 += dot4(w, b);
        w = LD4(w1i, j20 +  400 + 4 * k); gA1 += dot4(w, a); gB1 += dot4(w, b);
        w = LD4(w1i, j20 +  800 + 4 * k); gA2 += dot4(w, a); gB2 += dot4(w, b);
        w = LD4(w1i, j20 + 1200 + 4 * k); gA3 += dot4(w, a); gB3 += dot4(w, b);
      }
#pragma unroll
      for (int k = 0; k < 5; ++k) {
        a = LD4(hs1, eA20 + 4 * k);          // h1(t-1)
        b = LD4(hs1, eB20 + 4 * k);
        w = LD4(w1h, j20 +    0 + 4 * k); gA0 += dot4(w, a); gB0 += dot4(w, b);
        w = LD4(w1h, j20 +  400 + 4 * k); gA1 += dot4(w, a); gB1 += dot4(w, b);
        w = LD4(w1h, j20 +  800 + 4 * k); gA2 += dot4(w, a); gB2 += dot4(w, b);
        w = LD4(w1h, j20 + 1200 + 4 * k); gA3 += dot4(w, a); gB3 += dot4(w, b);
      }
      float iA = sigm(gA0), fA = sigm(gA1), gA = tanh_fast(gA2), oA = sigm(gA3);
      cA1 = fA * cA1 + iA * gA;
      float nhA = oA * tanh_fast(cA1);
      float iB = sigm(gB0), fB = sigm(gB1), gB = tanh_fast(gB2), oB = sigm(gB3);
      cB1 = fB * cB1 + iB * gB;
      float nhB = oB * tanh_fast(cB1);
      if (alive) { hs1[eA20 + j] = nhA; hs1[eB20 + j] = nhB; }
    }

    // ================= layer 2 =================
    {
      float4 bq = LD4(cbp2, j4);
      float gA0 = bq.x, gA1 = bq.y, gA2 = bq.z, gA3 = bq.w;
      float gB0 = bq.x, gB1 = bq.y, gB2 = bq.z, gB3 = bq.w;
#pragma unroll
      for (int k = 0; k < 5; ++k) {
        a = LD4(hs1, eA20 + 4 * k);          // fresh h1(t)
        b = LD4(hs1, eB20 + 4 * k);
        w = LD4(w2i, j20 +    0 + 4 * k); gA0 += dot4(w, a); gB0 += dot4(w, b);
        w = LD4(w2i, j20 +  400 + 4 * k); gA1 += dot4(w, a); gB1 += dot4(w, b);
        w = LD4(w2i, j20 +  800 + 4 * k); gA2 += dot4(w, a); gB2 += dot4(w, b);
        w = LD4(w2i, j20 + 1200 + 4 * k); gA3 += dot4(w, a); gB3 += dot4(w, b);
      }
#pragma unroll
      for (int k = 0; k < 5; ++k) {
        a = LD4(hs2, eA20 + 4 * k);          // h2(t-1)
        b = LD4(hs2, eB20 + 4 * k);
        w = LD4(w2h, j20 +    0 + 4 * k); gA0 += dot4(w, a); gB0 += dot4(w, b);
        w = LD4(w2h, j20 +  400 + 4 * k); gA1 += dot4(w, a); gB1 += dot4(w, b);
        w = LD4(w2h, j20 +  800 + 4 * k); gA2 += dot4(w, a); gB2 += dot4(w, b);
        w = LD4(w2h, j20 + 1200 + 4 * k); gA3 += dot4(w, a); gB3 += dot4(w, b);
      }
      float iA = sigm(gA0), fA = sigm(gA1), gA = tanh_fast(gA2), oA = sigm(gA3);
      cA2 = fA * cA2 + iA * gA;
      float nhA = oA * tanh_fast(cA2);
      float iB = sigm(gB0), fB = sigm(gB1), gB = tanh_fast(gB2), oB = sigm(gB3);
      cB2 = fB * cB2 + iB * gB;
      float nhB = oB * tanh_fast(cB2);
      if (alive) { hs2[eA20 + j] = nhA; hs2[eB20 + j] = nhB; }
    }
  }

  // ================= FC head =================
  {
    float sA = fc1b[j], sB = fc1b[j];
#pragma unroll
    for (int k = 0; k < 5; ++k) {
      float4 a = LD4(hs2, eA20 + 4 * k);
      float4 b = LD4(hs2, eB20 + 4 * k);
      float4 w = *(const float4*)(fc1w + j20 + 4 * k);
      sA += dot4(w, a); sB += dot4(w, b);
    }
    sA = fmaxf(sA, 0.0f); sB = fmaxf(sB, 0.0f);
    if (alive) { hs0[eA20 + j] = sA; hs0[eB20 + j] = sB; }  // stage fc1 out
  }
  if (alive && j == 0) {
    float rA = fc2b[0], rB = fc2b[0];
#pragma unroll
    for (int k = 0; k < 5; ++k) {
      float4 a = LD4(hs0, eA20 + 4 * k);
      float4 b = LD4(hs0, eB20 + 4 * k);
      float4 w = *(const float4*)(fc2w + 4 * k);
      rA += dot4(w, a); rB += dot4(w, b);
    }
    if (egA < B_TOT) out[egA] = rA;
    if (egB < B_TOT) out[egB] = rB;
  }
}

extern "C" void kernel_launch(void* const* d_in, const int* in_sizes, int n_in,
                              void* d_out, int out_size, void* d_ws, size_t ws_size,
                              hipStream_t stream) {
  const float* x    = (const float*)d_in[0];
  const float* Wih0 = (const float*)d_in[1];
  const float* Whh0 = (const float*)d_in[2];
  const float* bih0 = (const float*)d_in[3];
  const float* bhh0 = (const float*)d_in[4];
  const float* Wih1 = (const float*)d_in[5];
  const float* Whh1 = (const float*)d_in[6];
  const float* bih1 = (const float*)d_in[7];
  const float* bhh1 = (const float*)d_in[8];
  const float* Wih2 = (const float*)d_in[9];
  const float* Whh2 = (const float*)d_in[10];
  const float* bih2 = (const float*)d_in[11];
  const float* bhh2 = (const float*)d_in[12];
  const float* fc1w = (const float*)d_in[13];
  const float* fc1b = (const float*)d_in[14];
  const float* fc2w = (const float*)d_in[15];
  const float* fc2b = (const float*)d_in[16];
  float* out = (float*)d_out;

  const int nblk = (8192 + 11) / 12;   // 683
  hipLaunchKernelGGL(lstm3_fc_kernel, dim3(nblk), dim3(128), 0, stream,
                     x, Wih0, Whh0, bih0, bhh0,
                     Wih1, Whh1, bih1, bhh1,
                     Wih2, Whh2, bih2, bhh2,
                     fc1w, fc1b, fc2w, fc2b, out);
}

// Round 5
// 1240.428 us; speedup vs baseline: 6.8096x; 1.3850x over previous
//
#include <hip/hip_runtime.h>

// 3-layer LSTM (B=8192, T=336, F=8, H=20) + FC(20->20 relu) + FC(20->1).
//
// Round 5: fp16 LDS + v_dot2_f32_f16, E=4 elements per lane.
//  - R4 was LDS-pipe-bound (161 ds_read_b128/wave-step x 12cyc). fp16 halves
//    weight-read instructions and dot2 halves FMA count; E=4 amortizes each
//    weight row over 4 elements. Accumulation, biases, c-state all fp32;
//    only weights/h/x quantized to fp16 (RTNE).
//  - Wave = 3 groups x 20 unit-lanes (4 idle); group owns 4 elements.
//    Block = 64 thr (1 wave) = 12 elems; grid = 683; LDS ~28 KB.
//  - Row strides 80B (L0) / 112B (L1,L2): 16B-aligned sections, period-8
//    bank pattern over 20 lanes -> <=3-way aliasing.
//  - LICM-blocker (asm clobber) kept: proven fix for the R1-R3 spill disease.
//  - x(t+1) prefetched inside iteration t (loads issued ~3500cyc early).
//  - h exchanged wave-internally through LDS, no barriers in the loop.

#define T_LEN 336
#define B_TOT 8192

typedef _Float16 half_t;
typedef _Float16 h2 __attribute__((ext_vector_type(2)));

#define BC(f) __builtin_bit_cast(h2, (f))

#if __has_builtin(__builtin_amdgcn_fdot2)
#define FD(a, b, c) __builtin_amdgcn_fdot2((a), (b), (c), false)
#else
#define FD(a, b, c) ((float)(a)[0] * (float)(b)[0] + (float)(a)[1] * (float)(b)[1] + (c))
#endif

#define LDH4(arr, i) (*(const float4*)&(arr)[i])   // 8 f16
#define LDH2(arr, i) (*(const float2*)&(arr)[i])   // 4 f16
#define LD4F(arr, i) (*(const float4*)&(arr)[i])   // 4 f32

__device__ __forceinline__ float sigm(float x) {
  return __builtin_amdgcn_rcpf(1.0f + __builtin_amdgcn_exp2f(-1.4426950408889634f * x));
}
__device__ __forceinline__ float tanh_fast(float x) {
  return 2.0f * __builtin_amdgcn_rcpf(1.0f + __builtin_amdgcn_exp2f(-2.8853900817779268f * x)) - 1.0f;
}

// dot of 20 f16 (wa|wb|wc) with 20 f16 (ha|hb|hc), fp32 accumulate
__device__ __forceinline__ float dot20(float4 wa, float4 wb, float2 wc,
                                       float4 ha, float4 hb, float2 hc, float s) {
  s = FD(BC(wa.x), BC(ha.x), s); s = FD(BC(wa.y), BC(ha.y), s);
  s = FD(BC(wa.z), BC(ha.z), s); s = FD(BC(wa.w), BC(ha.w), s);
  s = FD(BC(wb.x), BC(hb.x), s); s = FD(BC(wb.y), BC(hb.y), s);
  s = FD(BC(wb.z), BC(hb.z), s); s = FD(BC(wb.w), BC(hb.w), s);
  s = FD(BC(wc.x), BC(hc.x), s); s = FD(BC(wc.y), BC(hc.y), s);
  return s;
}

// dot of f16 h-vector with fp32 weight float4s (FC head)
__device__ __forceinline__ float dot20_wf32(float4 f0, float4 f1, float4 f2, float4 f3, float4 f4,
                                            float4 ha, float4 hb, float2 hc, float s) {
  h2 p;
  p = BC(ha.x); s += f0.x*(float)p[0] + f0.y*(float)p[1];
  p = BC(ha.y); s += f0.z*(float)p[0] + f0.w*(float)p[1];
  p = BC(ha.z); s += f1.x*(float)p[0] + f1.y*(float)p[1];
  p = BC(ha.w); s += f1.z*(float)p[0] + f1.w*(float)p[1];
  p = BC(hb.x); s += f2.x*(float)p[0] + f2.y*(float)p[1];
  p = BC(hb.y); s += f2.z*(float)p[0] + f2.w*(float)p[1];
  p = BC(hb.z); s += f3.x*(float)p[0] + f3.y*(float)p[1];
  p = BC(hb.w); s += f3.z*(float)p[0] + f3.w*(float)p[1];
  p = BC(hc.x); s += f4.x*(float)p[0] + f4.y*(float)p[1];
  p = BC(hc.y); s += f4.z*(float)p[0] + f4.w*(float)p[1];
  return s;
}

// read a 20-f16 h vector (slot base s, f16 units; 48B stride outside)
#define RDH(A, B, C, arr, s) \
  float4 A = LDH4(arr, (s));      \
  float4 B = LDH4(arr, (s) + 8);  \
  float2 C = LDH2(arr, (s) + 16);

// L0 gate: row stride 40 f16 = [x 0..7 | h 8..27 | pad]
#define L0GATE(G, A0, A1, A2, A3) { \
  const int rb_ = (G * 20 + j) * 40; \
  float4 rx_ = LDH4(w0, rb_); \
  float4 ra_ = LDH4(w0, rb_ + 8), rb4_ = LDH4(w0, rb_ + 16); float2 rc_ = LDH2(w0, rb_ + 24); \
  A0 = dot20(ra_, rb4_, rc_, pa0, pb0, pc0, FD(BC(rx_.x), x00, FD(BC(rx_.y), x01, FD(BC(rx_.z), x02, FD(BC(rx_.w), x03, A0))))); \
  A1 = dot20(ra_, rb4_, rc_, pa1, pb1, pc1, FD(BC(rx_.x), x10, FD(BC(rx_.y), x11, FD(BC(rx_.z), x12, FD(BC(rx_.w), x13, A1))))); \
  A2 = dot20(ra_, rb4_, rc_, pa2, pb2, pc2, FD(BC(rx_.x), x20, FD(BC(rx_.y), x21, FD(BC(rx_.z), x22, FD(BC(rx_.w), x23, A2))))); \
  A3 = dot20(ra_, rb4_, rc_, pa3, pb3, pc3, FD(BC(rx_.x), x30, FD(BC(rx_.y), x31, FD(BC(rx_.z), x32, FD(BC(rx_.w), x33, A3))))); }

// L1/L2 gate: row stride 56 f16 = [ih 0..19 | pad | hh 24..43 | pad]
// ia*/ib*/ic* = fresh input h of 4 elems; ja*/jb*/jc* = this layer's h(t-1)
#define LGATE(W, G, A0, A1, A2, A3) { \
  const int rb_ = (G * 20 + j) * 56; \
  float4 u0_ = LDH4(W, rb_),      u1_ = LDH4(W, rb_ + 8);  float2 u2_ = LDH2(W, rb_ + 16); \
  float4 v0_ = LDH4(W, rb_ + 24), v1_ = LDH4(W, rb_ + 32); float2 v2_ = LDH2(W, rb_ + 40); \
  A0 = dot20(v0_, v1_, v2_, ja0, jb0, jc0, dot20(u0_, u1_, u2_, ia0, ib0, ic0, A0)); \
  A1 = dot20(v0_, v1_, v2_, ja1, jb1, jc1, dot20(u0_, u1_, u2_, ia1, ib1, ic1, A1)); \
  A2 = dot20(v0_, v1_, v2_, ja2, jb2, jc2, dot20(u0_, u1_, u2_, ia2, ib2, ic2, A2)); \
  A3 = dot20(v0_, v1_, v2_, ja3, jb3, jc3, dot20(u0_, u1_, u2_, ia3, ib3, ic3, A3)); }

#define CELL(GI, GF, GG, GO, C, ARR, S) { \
  float ig_ = sigm(GI), fg_ = sigm(GF), gv_ = tanh_fast(GG), ov_ = sigm(GO); \
  C = fg_ * C + ig_ * gv_; \
  if (alive) (ARR)[(S) + j] = (half_t)(ov_ * tanh_fast(C)); }

__global__ __launch_bounds__(64, 1) void lstm3_fc_kernel(
    const float* __restrict__ x,
    const float* __restrict__ Wih0, const float* __restrict__ Whh0,
    const float* __restrict__ bih0, const float* __restrict__ bhh0,
    const float* __restrict__ Wih1, const float* __restrict__ Whh1,
    const float* __restrict__ bih1, const float* __restrict__ bhh1,
    const float* __restrict__ Wih2, const float* __restrict__ Whh2,
    const float* __restrict__ bih2, const float* __restrict__ bhh2,
    const float* __restrict__ fc1w, const float* __restrict__ fc1b,
    const float* __restrict__ fc2w, const float* __restrict__ fc2b,
    float* __restrict__ out)
{
  __shared__ half_t w0[80 * 40];            // [x8 | h20 | pad12], 80B rows
  __shared__ half_t w1[80 * 56];            // [ih20 | pad4 | hh20 | pad12], 112B rows
  __shared__ half_t w2[80 * 56];
  __shared__ float  cbp0[80], cbp1[80], cbp2[80];      // f32 bias, packed [j*4+q]
  __shared__ half_t hs0[13 * 24], hs1[13 * 24], hs2[13 * 24];  // h, 48B stride
  __shared__ float  fcbuf[13 * 20];

  const int tid = threadIdx.x;

  // ---- stage weights to f16 LDS ----
  for (int i = tid; i < 640; i += 64) w0[(i >> 3) * 40 + (i & 7)] = (half_t)Wih0[i];
  for (int i = tid; i < 1600; i += 64) {
    int r = i / 20, k = i - 20 * r;
    w0[r * 40 + 8 + k]  = (half_t)Whh0[i];
    w1[r * 56 + k]      = (half_t)Wih1[i];
    w1[r * 56 + 24 + k] = (half_t)Whh1[i];
    w2[r * 56 + k]      = (half_t)Wih2[i];
    w2[r * 56 + 24 + k] = (half_t)Whh2[i];
  }
  for (int i = tid; i < 80; i += 64) {
    int q = i & 3, jj = i >> 2;
    cbp0[i] = bih0[q * 20 + jj] + bhh0[q * 20 + jj];
    cbp1[i] = bih1[q * 20 + jj] + bhh1[q * 20 + jj];
    cbp2[i] = bih2[q * 20 + jj] + bhh2[q * 20 + jj];
  }
  for (int i = tid; i < 312; i += 64) {
    hs0[i] = (half_t)0.f; hs1[i] = (half_t)0.f; hs2[i] = (half_t)0.f;
  }
  __syncthreads();   // only barrier (1-wave block; cheap)

  const int lane = tid;
  const int ew = lane / 20, j = lane - ew * 20;
  const bool alive = (ew < 3);
  const int sl0 = alive ? (ew * 4) : 12;   // idle lanes -> dummy slot 12
  const int sl1 = alive ? (sl0 + 1) : 12;
  const int sl2 = alive ? (sl0 + 2) : 12;
  const int sl3 = alive ? (sl0 + 3) : 12;
  const int eg0 = blockIdx.x * 12 + sl0;
  const int eg1 = blockIdx.x * 12 + sl1;
  const int eg2 = blockIdx.x * 12 + sl2;
  const int eg3 = blockIdx.x * 12 + sl3;

  const int s0 = sl0 * 24, s1 = sl1 * 24, s2 = sl2 * 24, s3 = sl3 * 24;

  const float* xp0 = x + (long)((eg0 < B_TOT) ? eg0 : (B_TOT - 1)) * (T_LEN * 8);
  const float* xp1 = x + (long)((eg1 < B_TOT) ? eg1 : (B_TOT - 1)) * (T_LEN * 8);
  const float* xp2 = x + (long)((eg2 < B_TOT) ? eg2 : (B_TOT - 1)) * (T_LEN * 8);
  const float* xp3 = x + (long)((eg3 < B_TOT) ? eg3 : (B_TOT - 1)) * (T_LEN * 8);

  float c00 = 0.f, c01 = 0.f, c02 = 0.f, c03 = 0.f;
  float c10 = 0.f, c11 = 0.f, c12 = 0.f, c13 = 0.f;
  float c20 = 0.f, c21 = 0.f, c22 = 0.f, c23 = 0.f;

  // preload x(t=0)
  float4 xa0 = *(const float4*)(xp0), xb0 = *(const float4*)(xp0 + 4);
  float4 xa1 = *(const float4*)(xp1), xb1 = *(const float4*)(xp1 + 4);
  float4 xa2 = *(const float4*)(xp2), xb2 = *(const float4*)(xp2 + 4);
  float4 xa3 = *(const float4*)(xp3), xb3 = *(const float4*)(xp3 + 4);

#pragma unroll 1
  for (int t = 0; t < T_LEN; ++t) {
    asm volatile("" ::: "memory");   // forbid LICM of LDS loads (R4 fix)

    // convert current x to f16 pairs
    h2 x00{(half_t)xa0.x, (half_t)xa0.y}, x01{(half_t)xa0.z, (half_t)xa0.w},
       x02{(half_t)xb0.x, (half_t)xb0.y}, x03{(half_t)xb0.z, (half_t)xb0.w};
    h2 x10{(half_t)xa1.x, (half_t)xa1.y}, x11{(half_t)xa1.z, (half_t)xa1.w},
       x12{(half_t)xb1.x, (half_t)xb1.y}, x13{(half_t)xb1.z, (half_t)xb1.w};
    h2 x20{(half_t)xa2.x, (half_t)xa2.y}, x21{(half_t)xa2.z, (half_t)xa2.w},
       x22{(half_t)xb2.x, (half_t)xb2.y}, x23{(half_t)xb2.z, (half_t)xb2.w};
    h2 x30{(half_t)xa3.x, (half_t)xa3.y}, x31{(half_t)xa3.z, (half_t)xa3.w},
       x32{(half_t)xb3.x, (half_t)xb3.y}, x33{(half_t)xb3.z, (half_t)xb3.w};

    // prefetch x(t+1) — consumed next iteration, ~full step of latency cover
    {
      int tn = (t + 1 < T_LEN) ? (t + 1) : t;
      xa0 = *(const float4*)(xp0 + tn * 8); xb0 = *(const float4*)(xp0 + tn * 8 + 4);
      xa1 = *(const float4*)(xp1 + tn * 8); xb1 = *(const float4*)(xp1 + tn * 8 + 4);
      xa2 = *(const float4*)(xp2 + tn * 8); xb2 = *(const float4*)(xp2 + tn * 8 + 4);
      xa3 = *(const float4*)(xp3 + tn * 8); xb3 = *(const float4*)(xp3 + tn * 8 + 4);
    }

    // ================= layer 0 =================
    {
      RDH(pa0, pb0, pc0, hs0, s0) RDH(pa1, pb1, pc1, hs0, s1)
      RDH(pa2, pb2, pc2, hs0, s2) RDH(pa3, pb3, pc3, hs0, s3)
      float4 bq = LD4F(cbp0, j * 4);
      float g0e0 = bq.x, g0e1 = bq.x, g0e2 = bq.x, g0e3 = bq.x;
      float g1e0 = bq.y, g1e1 = bq.y, g1e2 = bq.y, g1e3 = bq.y;
      float g2e0 = bq.z, g2e1 = bq.z, g2e2 = bq.z, g2e3 = bq.z;
      float g3e0 = bq.w, g3e1 = bq.w, g3e2 = bq.w, g3e3 = bq.w;
      L0GATE(0, g0e0, g0e1, g0e2, g0e3)
      L0GATE(1, g1e0, g1e1, g1e2, g1e3)
      L0GATE(2, g2e0, g2e1, g2e2, g2e3)
      L0GATE(3, g3e0, g3e1, g3e2, g3e3)
      CELL(g0e0, g1e0, g2e0, g3e0, c00, hs0, s0)
      CELL(g0e1, g1e1, g2e1, g3e1, c01, hs0, s1)
      CELL(g0e2, g1e2, g2e2, g3e2, c02, hs0, s2)
      CELL(g0e3, g1e3, g2e3, g3e3, c03, hs0, s3)
    }

    // ================= layer 1 =================
    {
      RDH(ia0, ib0, ic0, hs0, s0) RDH(ia1, ib1, ic1, hs0, s1)   // fresh h0(t)
      RDH(ia2, ib2, ic2, hs0, s2) RDH(ia3, ib3, ic3, hs0, s3)
      RDH(ja0, jb0, jc0, hs1, s0) RDH(ja1, jb1, jc1, hs1, s1)   // h1(t-1)
      RDH(ja2, jb2, jc2, hs1, s2) RDH(ja3, jb3, jc3, hs1, s3)
      float4 bq = LD4F(cbp1, j * 4);
      float g0e0 = bq.x, g0e1 = bq.x, g0e2 = bq.x, g0e3 = bq.x;
      float g1e0 = bq.y, g1e1 = bq.y, g1e2 = bq.y, g1e3 = bq.y;
      float g2e0 = bq.z, g2e1 = bq.z, g2e2 = bq.z, g2e3 = bq.z;
      float g3e0 = bq.w, g3e1 = bq.w, g3e2 = bq.w, g3e3 = bq.w;
      LGATE(w1, 0, g0e0, g0e1, g0e2, g0e3)
      LGATE(w1, 1, g1e0, g1e1, g1e2, g1e3)
      LGATE(w1, 2, g2e0, g2e1, g2e2, g2e3)
      LGATE(w1, 3, g3e0, g3e1, g3e2, g3e3)
      CELL(g0e0, g1e0, g2e0, g3e0, c10, hs1, s0)
      CELL(g0e1, g1e1, g2e1, g3e1, c11, hs1, s1)
      CELL(g0e2, g1e2, g2e2, g3e2, c12, hs1, s2)
      CELL(g0e3, g1e3, g2e3, g3e3, c13, hs1, s3)
    }

    // ================= layer 2 =================
    {
      RDH(ia0, ib0, ic0, hs1, s0) RDH(ia1, ib1, ic1, hs1, s1)   // fresh h1(t)
      RDH(ia2, ib2, ic2, hs1, s2) RDH(ia3, ib3, ic3, hs1, s3)
      RDH(ja0, jb0, jc0, hs2, s0) RDH(ja1, jb1, jc1, hs2, s1)   // h2(t-1)
      RDH(ja2, jb2, jc2, hs2, s2) RDH(ja3, jb3, jc3, hs2, s3)
      float4 bq = LD4F(cbp2, j * 4);
      float g0e0 = bq.x, g0e1 = bq.x, g0e2 = bq.x, g0e3 = bq.x;
      float g1e0 = bq.y, g1e1 = bq.y, g1e2 = bq.y, g1e3 = bq.y;
      float g2e0 = bq.z, g2e1 = bq.z, g2e2 = bq.z, g2e3 = bq.z;
      float g3e0 = bq.w, g3e1 = bq.w, g3e2 = bq.w, g3e3 = bq.w;
      LGATE(w2, 0, g0e0, g0e1, g0e2, g0e3)
      LGATE(w2, 1, g1e0, g1e1, g1e2, g1e3)
      LGATE(w2, 2, g2e0, g2e1, g2e2, g2e3)
      LGATE(w2, 3, g3e0, g3e1, g3e2, g3e3)
      CELL(g0e0, g1e0, g2e0, g3e0, c20, hs2, s0)
      CELL(g0e1, g1e1, g2e1, g3e1, c21, hs2, s1)
      CELL(g0e2, g1e2, g2e2, g3e2, c22, hs2, s2)
      CELL(g0e3, g1e3, g2e3, g3e3, c23, hs2, s3)
    }
  }

  // ================= FC head =================
  {
    const float4* fw = (const float4*)(fc1w + j * 20);
    float4 f0 = fw[0], f1 = fw[1], f2 = fw[2], f3 = fw[3], f4 = fw[4];
    float fb = fc1b[j];
    RDH(za0, zb0, zc0, hs2, s0) RDH(za1, zb1, zc1, hs2, s1)
    RDH(za2, zb2, zc2, hs2, s2) RDH(za3, zb3, zc3, hs2, s3)
    float r0 = fmaxf(dot20_wf32(f0, f1, f2, f3, f4, za0, zb0, zc0, fb), 0.f);
    float r1 = fmaxf(dot20_wf32(f0, f1, f2, f3, f4, za1, zb1, zc1, fb), 0.f);
    float r2 = fmaxf(dot20_wf32(f0, f1, f2, f3, f4, za2, zb2, zc2, fb), 0.f);
    float r3 = fmaxf(dot20_wf32(f0, f1, f2, f3, f4, za3, zb3, zc3, fb), 0.f);
    if (alive) {
      fcbuf[sl0 * 20 + j] = r0; fcbuf[sl1 * 20 + j] = r1;
      fcbuf[sl2 * 20 + j] = r2; fcbuf[sl3 * 20 + j] = r3;
    }
  }
  if (alive && j == 0) {
    const float4* f2w = (const float4*)fc2w;
    float4 w0v = f2w[0], w1v = f2w[1], w2v = f2w[2], w3v = f2w[3], w4v = f2w[4];
    float b2 = fc2b[0];
#define FC2(S, EG)                                                         \
    {                                                                      \
      float4 a0 = LD4F(fcbuf, (S) * 20), a1 = LD4F(fcbuf, (S) * 20 + 4),   \
             a2 = LD4F(fcbuf, (S) * 20 + 8), a3 = LD4F(fcbuf, (S) * 20 + 12), \
             a4 = LD4F(fcbuf, (S) * 20 + 16);                              \
      float r = b2 + w0v.x*a0.x + w0v.y*a0.y + w0v.z*a0.z + w0v.w*a0.w     \
                   + w1v.x*a1.x + w1v.y*a1.y + w1v.z*a1.z + w1v.w*a1.w     \
                   + w2v.x*a2.x + w2v.y*a2.y + w2v.z*a2.z + w2v.w*a2.w     \
                   + w3v.x*a3.x + w3v.y*a3.y + w3v.z*a3.z + w3v.w*a3.w     \
                   + w4v.x*a4.x + w4v.y*a4.y + w4v.z*a4.z + w4v.w*a4.w;    \
      if ((EG) < B_TOT) out[EG] = r;                                       \
    }
    FC2(sl0, eg0) FC2(sl1, eg1) FC2(sl2, eg2) FC2(sl3, eg3)
#undef FC2
  }
}

extern "C" void kernel_launch(void* const* d_in, const int* in_sizes, int n_in,
                              void* d_out, int out_size, void* d_ws, size_t ws_size,
                              hipStream_t stream) {
  const float* x    = (const float*)d_in[0];
  const float* Wih0 = (const float*)d_in[1];
  const float* Whh0 = (const float*)d_in[2];
  const float* bih0 = (const float*)d_in[3];
  const float* bhh0 = (const float*)d_in[4];
  const float* Wih1 = (const float*)d_in[5];
  const float* Whh1 = (const float*)d_in[6];
  const float* bih1 = (const float*)d_in[7];
  const float* bhh1 = (const float*)d_in[8];
  const float* Wih2 = (const float*)d_in[9];
  const float* Whh2 = (const float*)d_in[10];
  const float* bih2 = (const float*)d_in[11];
  const float* bhh2 = (const float*)d_in[12];
  const float* fc1w = (const float*)d_in[13];
  const float* fc1b = (const float*)d_in[14];
  const float* fc2w = (const float*)d_in[15];
  const float* fc2b = (const float*)d_in[16];
  float* out = (float*)d_out;

  const int nblk = (8192 + 11) / 12;   // 683 blocks x 1 wave x 12 elems
  hipLaunchKernelGGL(lstm3_fc_kernel, dim3(nblk), dim3(64), 0, stream,
                     x, Wih0, Whh0, bih0, bhh0,
                     Wih1, Whh1, bih1, bhh1,
                     Wih2, Whh2, bih2, bhh2,
                     fc1w, fc1b, fc2w, fc2b, out);
}

// Round 6
// 626.014 us; speedup vs baseline: 13.4930x; 1.9815x over previous
//
#include <hip/hip_runtime.h>

// 3-layer LSTM (B=8192, T=336, F=8, H=20) + FC(20->20 relu) + FC(20->1).
//
// Round 6: MFMA restructure. Wave = 16 batch elements; per step each layer is
// gates[80x16] = W[80xK] @ z[Kx16] on v_mfma_f32_16x16x32_f16 (fp32 acc).
//  - Weights live in VGPRs as 25 A-fragments (gathered once): zero weight
//    LDS traffic (R4/R5 bottleneck). Biases live as 15 C-init fragments.
//  - Tiles are GATE-ALIGNED: tiles 0..3 = units 0..15 of gates i,f,g,o;
//    tile 4 = leftover units 16..19 packed 4 rows/gate. So a lane holds
//    i,f,g,o of the same (unit,elem) in the same reg -> in-register cell
//    update (leftover tile bounced through a 1KB LDS buffer).
//  - z buffers in LDS, transposed per element: zT[elem][k] halves, so a
//    B-fragment read is one contiguous ds_read_b128 (k = 8q..8q+7).
//    z0 = [x(8)|h0(20)|0(4)] (K=32); z1 = [h0|h1|0(24)], z2 = [h1|h2|0(24)]
//    (K=64, 2 chunks; A is zero where z is padded).
//  - Single wave per block: all LDS exchange is wave-internal, in-order,
//    ZERO barriers. Grid 512 x 64 thr. LDS ~6.5 KB. LICM clobber kept.
//
// Layouts (m89/m120-verified, dtype-independent):
//   A[m][k]: m=lane&15, k=(lane>>4)*8+j   B[k][n]: n=lane&15, k=(lane>>4)*8+j
//   D[m][n]: n=lane&15, m=(lane>>4)*4+reg

#define T_LEN 336

typedef _Float16 f16;
typedef _Float16 f16x2 __attribute__((ext_vector_type(2)));
typedef _Float16 f16x4 __attribute__((ext_vector_type(4)));
typedef _Float16 f16x8 __attribute__((ext_vector_type(8)));
typedef float f32x4 __attribute__((ext_vector_type(4)));

#define MFMA(a, b, c) __builtin_amdgcn_mfma_f32_16x16x32_f16((a), (b), (c), 0, 0, 0)

__device__ __forceinline__ float sigm(float x) {
  return __builtin_amdgcn_rcpf(1.0f + __builtin_amdgcn_exp2f(-1.4426950408889634f * x));
}
__device__ __forceinline__ float tanh_fast(float x) {
  return 2.0f * __builtin_amdgcn_rcpf(1.0f + __builtin_amdgcn_exp2f(-2.8853900817779268f * x)) - 1.0f;
}

// unit-aligned tiles: lane(q,n) holds units 4q+r (reg r), elem n — all 4 gates in-lane
#define CELLS4(DI, DF, DG, DO, C0, C1, C2, C3, HV) {                                        \
  { float i_=sigm((DI)[0]), f_=sigm((DF)[0]), g_=tanh_fast((DG)[0]), o_=sigm((DO)[0]);      \
    C0 = f_*C0 + i_*g_; (HV)[0] = (f16)(o_*tanh_fast(C0)); }                                \
  { float i_=sigm((DI)[1]), f_=sigm((DF)[1]), g_=tanh_fast((DG)[1]), o_=sigm((DO)[1]);      \
    C1 = f_*C1 + i_*g_; (HV)[1] = (f16)(o_*tanh_fast(C1)); }                                \
  { float i_=sigm((DI)[2]), f_=sigm((DF)[2]), g_=tanh_fast((DG)[2]), o_=sigm((DO)[2]);      \
    C2 = f_*C2 + i_*g_; (HV)[2] = (f16)(o_*tanh_fast(C2)); }                                \
  { float i_=sigm((DI)[3]), f_=sigm((DF)[3]), g_=tanh_fast((DG)[3]), o_=sigm((DO)[3]);      \
    C3 = f_*C3 + i_*g_; (HV)[3] = (f16)(o_*tanh_fast(C3)); } }

// leftover tile: writer lane(q,n) has gate-q of units 16..19 (regs 0..3); bounce
// through gbufL so lane(q,n) can assemble all 4 gates of unit 16+q, elem n.
#define CELL_L(DL, CL, HOUT) {                                                              \
  *(f32x4*)&gbufL[(q * 16 + n) * 4] = (DL);                                                 \
  float i_ = sigm(gbufL[n * 4 + q]);                                                        \
  float f_ = sigm(gbufL[(16 + n) * 4 + q]);                                                 \
  float g_ = tanh_fast(gbufL[(32 + n) * 4 + q]);                                            \
  float o_ = sigm(gbufL[(48 + n) * 4 + q]);                                                 \
  CL = f_*CL + i_*g_; HOUT = (f16)(o_*tanh_fast(CL)); }

__global__ __launch_bounds__(64, 1) void lstm3_mfma_kernel(
    const float* __restrict__ x,
    const float* __restrict__ Wih0, const float* __restrict__ Whh0,
    const float* __restrict__ bih0, const float* __restrict__ bhh0,
    const float* __restrict__ Wih1, const float* __restrict__ Whh1,
    const float* __restrict__ bih1, const float* __restrict__ bhh1,
    const float* __restrict__ Wih2, const float* __restrict__ Whh2,
    const float* __restrict__ bih2, const float* __restrict__ bhh2,
    const float* __restrict__ fc1w, const float* __restrict__ fc1b,
    const float* __restrict__ fc2w, const float* __restrict__ fc2b,
    float* __restrict__ out)
{
  __shared__ __align__(16) f16 zT0[16 * 32];   // [elem][k]: x8|h0 20|pad4
  __shared__ __align__(16) f16 zT1[16 * 64];   // h0 20|h1 20|pad24
  __shared__ __align__(16) f16 zT2[16 * 64];   // h1 20|h2 20|pad24
  __shared__ __align__(16) float gbufL[4 * 16 * 4];   // [gate][elem][reg]
  __shared__ __align__(16) float pbuf[16 * 4];        // fc2 partials [elem][q]

  const int lane = threadIdx.x;
  const int n = lane & 15;          // elem within wave / M-N index
  const int q = lane >> 4;          // quad: K-octet (A/B), row-quad (C/D)

  // ---- zero z buffers (pads must be 0; h(0)=0) ----
  {
    f16x8 zer;
#pragma unroll
    for (int j = 0; j < 8; ++j) zer[j] = (f16)0.f;
    ((f16x8*)zT0)[lane] = zer;
    ((f16x8*)zT1)[lane] = zer; ((f16x8*)zT1)[lane + 64] = zer;
    ((f16x8*)zT2)[lane] = zer; ((f16x8*)zT2)[lane + 64] = zer;
  }

  // ---- one-time register-resident weight/bias fragments ----
  // tile row map: T<4 -> gate T, units 0..15 (row T*20+m); T==4 -> gate m>>2, unit 16+(m&3)
  auto rowmap = [](int T, int m) { return T < 4 ? T * 20 + m : (m >> 2) * 20 + 16 + (m & 3); };
  auto gA0 = [&](int T) {          // layer 0: K=32 = [x8 | h20 | pad4]
    int row = rowmap(T, n);
    f16x8 r;
#pragma unroll
    for (int j = 0; j < 8; ++j) {
      int k = q * 8 + j;
      float v = (k < 8) ? Wih0[row * 8 + k] : (k < 28 ? Whh0[row * 20 + k - 8] : 0.f);
      r[j] = (f16)v;
    }
    return r;
  };
  auto gA = [&](const float* Wih, const float* Whh, int T, int c) {   // K chunks of [ih20|hh20|pad24]
    int row = rowmap(T, n);
    f16x8 r;
#pragma unroll
    for (int j = 0; j < 8; ++j) {
      int k = c * 32 + q * 8 + j;
      float v = (k < 20) ? Wih[row * 20 + k] : (k < 40 ? Whh[row * 20 + k - 20] : 0.f);
      r[j] = (f16)v;
    }
    return r;
  };
  auto gBias = [&](const float* bi, const float* bh, int T) {
    f32x4 r;
#pragma unroll
    for (int j = 0; j < 4; ++j) {
      int row = rowmap(T, q * 4 + j);
      r[j] = bi[row] + bh[row];
    }
    return r;
  };

  const f16x8 A00 = gA0(0), A01 = gA0(1), A02 = gA0(2), A03 = gA0(3), A04 = gA0(4);
  const f16x8 W10a = gA(Wih1, Whh1, 0, 0), W10b = gA(Wih1, Whh1, 0, 1);
  const f16x8 W11a = gA(Wih1, Whh1, 1, 0), W11b = gA(Wih1, Whh1, 1, 1);
  const f16x8 W12a = gA(Wih1, Whh1, 2, 0), W12b = gA(Wih1, Whh1, 2, 1);
  const f16x8 W13a = gA(Wih1, Whh1, 3, 0), W13b = gA(Wih1, Whh1, 3, 1);
  const f16x8 W14a = gA(Wih1, Whh1, 4, 0), W14b = gA(Wih1, Whh1, 4, 1);
  const f16x8 W20a = gA(Wih2, Whh2, 0, 0), W20b = gA(Wih2, Whh2, 0, 1);
  const f16x8 W21a = gA(Wih2, Whh2, 1, 0), W21b = gA(Wih2, Whh2, 1, 1);
  const f16x8 W22a = gA(Wih2, Whh2, 2, 0), W22b = gA(Wih2, Whh2, 2, 1);
  const f16x8 W23a = gA(Wih2, Whh2, 3, 0), W23b = gA(Wih2, Whh2, 3, 1);
  const f16x8 W24a = gA(Wih2, Whh2, 4, 0), W24b = gA(Wih2, Whh2, 4, 1);

  const f32x4 Bi0 = gBias(bih0, bhh0, 0), Bf0 = gBias(bih0, bhh0, 1),
              Bg0 = gBias(bih0, bhh0, 2), Bo0 = gBias(bih0, bhh0, 3), BL0 = gBias(bih0, bhh0, 4);
  const f32x4 Bi1 = gBias(bih1, bhh1, 0), Bf1 = gBias(bih1, bhh1, 1),
              Bg1 = gBias(bih1, bhh1, 2), Bo1 = gBias(bih1, bhh1, 3), BL1 = gBias(bih1, bhh1, 4);
  const f32x4 Bi2 = gBias(bih2, bhh2, 0), Bf2 = gBias(bih2, bhh2, 1),
              Bg2 = gBias(bih2, bhh2, 2), Bo2 = gBias(bih2, bhh2, 3), BL2 = gBias(bih2, bhh2, 4);

  // c-state: units 4q..4q+3 (tile regs) + unit 16+q (leftover), per layer
  float c00 = 0.f, c01 = 0.f, c02 = 0.f, c03 = 0.f, cL0 = 0.f;
  float c10 = 0.f, c11 = 0.f, c12 = 0.f, c13 = 0.f, cL1 = 0.f;
  float c20 = 0.f, c21 = 0.f, c22 = 0.f, c23 = 0.f, cL2 = 0.f;

  // x: lane(q,n) stages features 2q, 2q+1 of elem n
  const float* xp = x + (size_t)(blockIdx.x * 16 + n) * (T_LEN * 8) + 2 * q;
  float2 xr = *(const float2*)(xp);   // t=0 preload

#pragma unroll 1
  for (int t = 0; t < T_LEN; ++t) {
    asm volatile("" ::: "memory");   // forbid cross-iteration LDS-load hoisting (R4 fix)

    // stage x(t) into z0, prefetch x(t+1)
    {
      f16x2 xh; xh[0] = (f16)xr.x; xh[1] = (f16)xr.y;
      *(f16x2*)&zT0[n * 32 + 2 * q] = xh;
      int tn = (t < T_LEN - 1) ? t + 1 : t;
      xr = *(const float2*)(xp + tn * 8);
    }

    // ================= layer 0 (K=32, 1 chunk) =================
    {
      f16x8 b0 = *(const f16x8*)&zT0[n * 32 + q * 8];
      f32x4 di = MFMA(A00, b0, Bi0);
      f32x4 df = MFMA(A01, b0, Bf0);
      f32x4 dg = MFMA(A02, b0, Bg0);
      f32x4 dn = MFMA(A03, b0, Bo0);
      f32x4 dl = MFMA(A04, b0, BL0);
      f16x4 hv;
      CELLS4(di, df, dg, dn, c00, c01, c02, c03, hv)
      *(f16x4*)&zT0[n * 32 + 8 + q * 4] = hv;    // self input next step
      *(f16x4*)&zT1[n * 64 + q * 4]     = hv;    // layer-1 input now
      f16 hl;
      CELL_L(dl, cL0, hl)
      zT0[n * 32 + 24 + q] = hl;
      zT1[n * 64 + 16 + q] = hl;
    }

    // ================= layer 1 (K=64, 2 chunks) =================
    {
      f16x8 ba = *(const f16x8*)&zT1[n * 64 + q * 8];
      f16x8 bb = *(const f16x8*)&zT1[n * 64 + 32 + q * 8];
      f32x4 di = MFMA(W10b, bb, MFMA(W10a, ba, Bi1));
      f32x4 df = MFMA(W11b, bb, MFMA(W11a, ba, Bf1));
      f32x4 dg = MFMA(W12b, bb, MFMA(W12a, ba, Bg1));
      f32x4 dn = MFMA(W13b, bb, MFMA(W13a, ba, Bo1));
      f32x4 dl = MFMA(W14b, bb, MFMA(W14a, ba, BL1));
      f16x4 hv;
      CELLS4(di, df, dg, dn, c10, c11, c12, c13, hv)
      *(f16x4*)&zT1[n * 64 + 20 + q * 4] = hv;   // self
      *(f16x4*)&zT2[n * 64 + q * 4]      = hv;   // layer-2 input
      f16 hl;
      CELL_L(dl, cL1, hl)
      zT1[n * 64 + 36 + q] = hl;
      zT2[n * 64 + 16 + q] = hl;
    }

    // ================= layer 2 (K=64, 2 chunks) =================
    {
      f16x8 ba = *(const f16x8*)&zT2[n * 64 + q * 8];
      f16x8 bb = *(const f16x8*)&zT2[n * 64 + 32 + q * 8];
      f32x4 di = MFMA(W20b, bb, MFMA(W20a, ba, Bi2));
      f32x4 df = MFMA(W21b, bb, MFMA(W21a, ba, Bf2));
      f32x4 dg = MFMA(W22b, bb, MFMA(W22a, ba, Bg2));
      f32x4 dn = MFMA(W23b, bb, MFMA(W23a, ba, Bo2));
      f32x4 dl = MFMA(W24b, bb, MFMA(W24a, ba, BL2));
      f16x4 hv;
      CELLS4(di, df, dg, dn, c20, c21, c22, c23, hv)
      *(f16x4*)&zT2[n * 64 + 20 + q * 4] = hv;   // self (final h2 lives here)
      f16 hl;
      CELL_L(dl, cL2, hl)
      zT2[n * 64 + 36 + q] = hl;
    }
  }

  // ================= FC head =================
  // h2(T-1) for elem n = zT2[n][20..39]; lane(q,n) computes fc1 rows d=5q..5q+4
  {
    f16x4 hv0 = *(const f16x4*)&zT2[n * 64 + 20];
    f16x4 hv1 = *(const f16x4*)&zT2[n * 64 + 24];
    f16x4 hv2 = *(const f16x4*)&zT2[n * 64 + 28];
    f16x4 hv3 = *(const f16x4*)&zT2[n * 64 + 32];
    f16x4 hv4 = *(const f16x4*)&zT2[n * 64 + 36];
    float p = 0.f;
#pragma unroll
    for (int i = 0; i < 5; ++i) {
      int d = q * 5 + i;
      const float* wr = fc1w + d * 20;
      float s = fc1b[d]
        + wr[0]  * (float)hv0[0] + wr[1]  * (float)hv0[1] + wr[2]  * (float)hv0[2] + wr[3]  * (float)hv0[3]
        + wr[4]  * (float)hv1[0] + wr[5]  * (float)hv1[1] + wr[6]  * (float)hv1[2] + wr[7]  * (float)hv1[3]
        + wr[8]  * (float)hv2[0] + wr[9]  * (float)hv2[1] + wr[10] * (float)hv2[2] + wr[11] * (float)hv2[3]
        + wr[12] * (float)hv3[0] + wr[13] * (float)hv3[1] + wr[14] * (float)hv3[2] + wr[15] * (float)hv3[3]
        + wr[16] * (float)hv4[0] + wr[17] * (float)hv4[1] + wr[18] * (float)hv4[2] + wr[19] * (float)hv4[3];
      p += fc2w[d] * fmaxf(s, 0.f);
    }
    pbuf[n * 4 + q] = p;
  }
  if (q == 0) {
    f32x4 pv = *(const f32x4*)&pbuf[n * 4];
    out[blockIdx.x * 16 + n] = pv[0] + pv[1] + pv[2] + pv[3] + fc2b[0];
  }
}

extern "C" void kernel_launch(void* const* d_in, const int* in_sizes, int n_in,
                              void* d_out, int out_size, void* d_ws, size_t ws_size,
                              hipStream_t stream) {
  const float* x    = (const float*)d_in[0];
  const float* Wih0 = (const float*)d_in[1];
  const float* Whh0 = (const float*)d_in[2];
  const float* bih0 = (const float*)d_in[3];
  const float* bhh0 = (const float*)d_in[4];
  const float* Wih1 = (const float*)d_in[5];
  const float* Whh1 = (const float*)d_in[6];
  const float* bih1 = (const float*)d_in[7];
  const float* bhh1 = (const float*)d_in[8];
  const float* Wih2 = (const float*)d_in[9];
  const float* Whh2 = (const float*)d_in[10];
  const float* bih2 = (const float*)d_in[11];
  const float* bhh2 = (const float*)d_in[12];
  const float* fc1w = (const float*)d_in[13];
  const float* fc1b = (const float*)d_in[14];
  const float* fc2w = (const float*)d_in[15];
  const float* fc2b = (const float*)d_in[16];
  float* out = (float*)d_out;

  hipLaunchKernelGGL(lstm3_mfma_kernel, dim3(8192 / 16), dim3(64), 0, stream,
                     x, Wih0, Whh0, bih0, bhh0,
                     Wih1, Whh1, bih1, bhh1,
                     Wih2, Whh2, bih2, bhh2,
                     fc1w, fc1b, fc2w, fc2b, out);
}